// Round 11
// baseline (209.074 us; speedup 1.0000x reference)
//
#include <hip/hip_runtime.h>
#include <cstdint>
#include <cstddef>

// ---------------------------------------------------------------------------
// Style2ResidualBlock1DSrc: modulated conv1d (StyleGAN2-style) on MI355X.
// R13: collapse to 2 dispatches (gemm frozen at R12's verified best).
//  Evidence: R12 confirmed ~8-10us/launch gap; style exists only to feed s.
//  s is recomputed redundantly inside each consumer block (no cross-block
//  dependency -> no grid barrier, R6 failure mode does not apply):
//   - transpose blocks (1024, 4 seq t-tiles each): self-compute 64-row s
//     slice (64 FMA/thr + 64KB L2-hot style_w; 4-tile chunking keeps the
//     redundant sw traffic at 67MB not 268MB).
//   - demod blocks (64, b-keyed, o-quarter each): self-compute s[b][:]
//     (512 FMA/thr) then demod direct from weight (float4x3 per 4 i).
//     Run concurrent with transpose window -> hidden.
//   - weight blocks (512): Wb bf16 only (s-independent).
//  Gemm: R12 verbatim (56-57us; m97-structure ceiling, 6 variants stable).
// Factorization kept: A = bf16 Wb[3][512][512] L2-resident, s folded into
// xT at transpose time, demod applied in fp32 epilogue.
// ---------------------------------------------------------------------------

#define LIN_SCALE  0.0625f           // 1/sqrt(256)
#define CONV_SCALE 0.014731391f      // 1/sqrt(512*9)

#define B_   16
#define CIN  512
#define COUT 512
#define T_   2048
#define TP   2050                    // T + 2 pad rows

typedef __bf16 bf16x8 __attribute__((ext_vector_type(8)));
typedef float  f32x4  __attribute__((ext_vector_type(4)));
typedef unsigned short u16x8 __attribute__((ext_vector_type(8)));
typedef unsigned short u16x2 __attribute__((ext_vector_type(2)));

#define AS1 __attribute__((address_space(1)))
#define AS3 __attribute__((address_space(3)))

__device__ inline unsigned short f2bf(float f) {
  __bf16 h = (__bf16)f;              // RNE fptrunc
  return __builtin_bit_cast(unsigned short, h);
}

// ---------------- 1. fused prep: transpose(1024) | Wb(512) | demod(64) ----------------
// ids [0,1024):        transpose+pad+s-modulate, 4 seq 64-wide t-tiles,
//                      s-slice self-computed from c/style_w.
// ids [1024,1536):     Wb[k][o][:] bf16 base weight (s-independent).
// ids [1536,1600):     demod[b][o-quarter] with s[b][:] self-computed.
__global__ __launch_bounds__(256) void fused_prep_kernel(const float* __restrict__ x,
                                                         const float* __restrict__ c_src,
                                                         const float* __restrict__ c_trg,
                                                         const float* __restrict__ sw,
                                                         const float* __restrict__ sb,
                                                         const float* __restrict__ weight,
                                                         unsigned short* __restrict__ xT,
                                                         float* __restrict__ demod,
                                                         unsigned short* __restrict__ Wb) {
  __shared__ __align__(16) char smem[18944];
  const int id  = blockIdx.x;
  const int tid = threadIdx.x;

  if (id < 1024) {
    // ------------- transpose path: 16b x 8i0 x 8tc, 4 tiles each -------------
    float* tile    = (float*)smem;               // [64][65] = 16640 B
    float* c_lds   = (float*)(smem + 16640);     // 256 f32
    float* partial = (float*)(smem + 17664);     // 256 f32
    float* ss      = (float*)(smem + 18688);     // 64 f32
    const int b   = id >> 6;
    const int i0  = ((id >> 3) & 7) * 64;
    const int t0b = (id & 7) * 256;

    // s-slice: s[b][i0+il] = LIN_SCALE * dot(sw[i0+il], c[b]) + sb[i0+il]
    c_lds[tid] = (tid < 128) ? c_src[b * 128 + tid] : c_trg[b * 128 + tid - 128];
    __syncthreads();
    {
      const int il = tid & 63, q = tid >> 6;     // 4 quarters of 64
      const f32x4* swr = (const f32x4*)(sw + (size_t)(i0 + il) * 256 + q * 64);
      const f32x4* cq  = (const f32x4*)(c_lds + q * 64);
      float p = 0.f;
      #pragma unroll
      for (int j = 0; j < 16; ++j) {
        const f32x4 wv = swr[j], cv = cq[j];
        p += wv.x * cv.x + wv.y * cv.y + wv.z * cv.z + wv.w * cv.w;
      }
      partial[q * 64 + il] = p;
    }
    __syncthreads();
    if (tid < 64)
      ss[tid] = LIN_SCALE * (partial[tid] + partial[64 + tid] + partial[128 + tid]
                           + partial[192 + tid]) + sb[i0 + tid];
    // fused zero-pad of rows 0 and 2049 (no barrier dependency on ss)
    if (t0b == 0 && tid < 8)
      *(u16x8*)&xT[(size_t)b * TP * CIN + i0 + tid * 8] = (u16x8){0,0,0,0,0,0,0,0};
    if (t0b == T_ - 256 && tid < 8)
      *(u16x8*)&xT[((size_t)b * TP + TP - 1) * CIN + i0 + tid * 8] = (u16x8){0,0,0,0,0,0,0,0};
    __syncthreads();

    const int lr = tid >> 4;            // 0..15
    const int lc = (tid & 15) * 4;      // float4
    const int st = tid >> 3;            // 0..31
    const int si = (tid & 7) * 8;       // 16B
    float sv[8];
    #pragma unroll
    for (int q = 0; q < 8; ++q) sv[q] = ss[si + q];

    for (int u = 0; u < 4; ++u) {
      const int t0 = t0b + u * 64;
      const float* xb = x + ((size_t)b * CIN + i0) * T_ + t0;
      #pragma unroll
      for (int p = 0; p < 4; ++p) {
        const int r = p * 16 + lr;
        const float4 v = *(const float4*)(xb + (size_t)r * T_ + lc);
        tile[r * 65 + lc + 0] = v.x; tile[r * 65 + lc + 1] = v.y;
        tile[r * 65 + lc + 2] = v.z; tile[r * 65 + lc + 3] = v.w;
      }
      __syncthreads();
      unsigned short* xTb = xT + ((size_t)b * TP + 1 + t0) * CIN + i0;
      #pragma unroll
      for (int p = 0; p < 2; ++p) {
        const int t = p * 32 + st;
        u16x8 v;
        #pragma unroll
        for (int q = 0; q < 8; ++q) v[q] = f2bf(tile[(si + q) * 65 + t] * sv[q]);
        *(u16x8*)&xTb[(size_t)t * CIN + si] = v;
      }
      __syncthreads();                  // guard tile overwrite next iter
    }
  } else if (id < 1536) {
    // ------------------ Wb path (s-independent) ------------------
    const int o = id - 1024;
    float* wsh = (float*)smem;                   // 1536 f32
    #pragma unroll
    for (int j = tid; j < 384; j += 256)
      ((float4*)wsh)[j] = ((const float4*)(weight + (size_t)o * 1536))[j];
    __syncthreads();
    float wr[6];
    #pragma unroll
    for (int q = 0; q < 6; ++q) wr[q] = wsh[tid * 6 + q] * CONV_SCALE;
    #pragma unroll
    for (int k = 0; k < 3; ++k) {
      u16x2 v;
      v.x = f2bf(wr[k]);
      v.y = f2bf(wr[3 + k]);
      *(u16x2*)&Wb[((size_t)(k * 512 + o)) * 512 + 2 * tid] = v;
    }
  } else {
    // ------------------ demod path: 16b x 4 o-quarters ------------------
    const int idx = id - 1536;
    const int b = idx >> 2;
    const int obase = (idx & 3) * 128;
    float* c_lds = (float*)smem;                 // 256 f32
    float* s_lds = (float*)(smem + 1024);        // 512 f32

    c_lds[tid] = (tid < 128) ? c_src[b * 128 + tid] : c_trg[b * 128 + tid - 128];
    __syncthreads();
    // s[b][i], i = tid, tid+256 (full serial f32x4 dot per thread)
    #pragma unroll
    for (int h = 0; h < 2; ++h) {
      const int i = h * 256 + tid;
      const f32x4* swr = (const f32x4*)(sw + (size_t)i * 256);
      const f32x4* cv4 = (const f32x4*)c_lds;
      float acc = 0.f;
      #pragma unroll 16
      for (int j = 0; j < 64; ++j) {
        const f32x4 wv = swr[j], cv = cv4[j];
        acc += wv.x * cv.x + wv.y * cv.y + wv.z * cv.z + wv.w * cv.w;
      }
      s_lds[i] = LIN_SCALE * acc + sb[i];
    }
    __syncthreads();
    // demod[b][o]: o = obase + (tid>>1), i-half = tid&1
    const int o = obase + (tid >> 1);
    const int half = tid & 1;
    const f32x4* wrow = (const f32x4*)(weight + (size_t)o * 1536 + half * 768);
    const float* sh = s_lds + half * 256;
    float ssq = 0.f;
    #pragma unroll 8
    for (int ii = 0; ii < 64; ++ii) {            // 4 i per iter: 3 f32x4
      const f32x4 a = wrow[ii * 3 + 0];
      const f32x4 bq = wrow[ii * 3 + 1];
      const f32x4 c4 = wrow[ii * 3 + 2];
      const float s0 = sh[ii * 4 + 0], s1 = sh[ii * 4 + 1];
      const float s2 = sh[ii * 4 + 2], s3 = sh[ii * 4 + 3];
      float v;
      v = CONV_SCALE * a.x  * s0; ssq += v * v;
      v = CONV_SCALE * a.y  * s0; ssq += v * v;
      v = CONV_SCALE * a.z  * s0; ssq += v * v;
      v = CONV_SCALE * a.w  * s1; ssq += v * v;
      v = CONV_SCALE * bq.x * s1; ssq += v * v;
      v = CONV_SCALE * bq.y * s1; ssq += v * v;
      v = CONV_SCALE * bq.z * s2; ssq += v * v;
      v = CONV_SCALE * bq.w * s2; ssq += v * v;
      v = CONV_SCALE * c4.x * s2; ssq += v * v;
      v = CONV_SCALE * c4.y * s3; ssq += v * v;
      v = CONV_SCALE * c4.z * s3; ssq += v * v;
      v = CONV_SCALE * c4.w * s3; ssq += v * v;
    }
    ssq += __shfl_xor(ssq, 1, 64);               // pair-sum the two halves
    if (half == 0) demod[(size_t)b * 512 + o] = rsqrtf(ssq + 1e-8f);
  }
}

// ---------------- 2. main GEMM: R12 verbatim (2-barrier, swapped operands) ----------------
// out[b][o0+wm+ni*16+oc][t0+wn+mi*16+tr..+3] = demod * acc[mi][ni]
// acc = mfma(xT_frag (A-op, t rows), Wb_frag (B-op, o cols)) -> D rows = t.
// Staging: lA[3][128][32], lB[258][32], chunk-swz c^((row>>1)&3).
__global__ __launch_bounds__(256, 2) void gemm_kernel(const unsigned short* __restrict__ Wb,
                                                      const unsigned short* __restrict__ xT,
                                                      const float* __restrict__ demod,
                                                      float* __restrict__ out) {
  __shared__ unsigned short lA[3 * 128 * 32];   // 24576 B
  __shared__ unsigned short lB[258 * 32];       // 16512 B

  // XCD b-grouping: 512 blocks; ids == xcd (mod 8); 2 batches per XCD.
  const int id  = blockIdx.x;
  const int xcd = id & 7;
  const int j   = id >> 3;                 // 0..63
  const int b   = xcd + 8 * (j >> 5);      // 0..15
  const int r   = j & 31;
  const int o0  = (r >> 3) * 128;          // 4 o-blocks
  const int t0  = (r & 7) * 256;           // 8 t-blocks

  const int tid  = threadIdx.x;
  const int lane = tid & 63;
  const int wm   = ((tid >> 6) & 1) * 64;  // wave o offset
  const int wn   = (tid >> 7) * 128;       // wave t offset
  const int rl   = lane & 15;
  const int kc   = lane >> 4;              // chunk 0..3 within 32-wide row

  const unsigned short* gW = Wb + (size_t)o0 * 512;            // batch-independent
  const unsigned short* gX = xT + ((size_t)b * TP + t0) * CIN;

  f32x4 acc[8][4];                         // [t-frag][o-frag]
  #pragma unroll
  for (int i = 0; i < 8; ++i)
    #pragma unroll
    for (int jj = 0; jj < 4; ++jj) acc[i][jj] = (f32x4){0.f, 0.f, 0.f, 0.f};

  for (int kk = 0; kk < 16; ++kk) {
    const int i0 = kk * 32;
    __syncthreads();                       // previous compute done
    // A: 1536 16B-chunks, 6 per thread. chunk ci=(tap*128+ar)*4+c
    #pragma unroll
    for (int q = 0; q < 6; ++q) {
      const int ci  = q * 256 + tid;
      const int row = ci >> 2;             // tap*128 + ar
      const int tap = row >> 7;
      const int ar  = row & 127;
      const int gc  = ((ci & 3) ^ ((ar >> 1) & 3)) * 8;
      __builtin_amdgcn_global_load_lds(
          (const AS1 void*)(gW + (size_t)tap * 262144 + (size_t)ar * 512 + i0 + gc),
          (AS3 void*)(&lA[ci * 8]), 16, 0, 0);
    }
    // B: 258 rows x 4 chunks = 1032; 4 per thread + tail 8
    #pragma unroll
    for (int q = 0; q < 4; ++q) {
      const int ci  = q * 256 + tid;
      const int row = ci >> 2;
      const int gc  = ((ci & 3) ^ ((row >> 1) & 3)) * 8;
      __builtin_amdgcn_global_load_lds(
          (const AS1 void*)(gX + (size_t)row * CIN + i0 + gc),
          (AS3 void*)(&lB[ci * 8]), 16, 0, 0);
    }
    if (tid < 8) {
      const int ci  = 1024 + tid;
      const int row = ci >> 2;             // 256, 257
      const int gc  = ((ci & 3) ^ ((row >> 1) & 3)) * 8;
      __builtin_amdgcn_global_load_lds(
          (const AS1 void*)(gX + (size_t)row * CIN + i0 + gc),
          (AS3 void*)(&lB[ci * 8]), 16, 0, 0);
    }
    __syncthreads();                       // staging visible

    #pragma unroll
    for (int tap = 0; tap < 3; ++tap) {
      bf16x8 wf[4], xf[8];
      #pragma unroll
      for (int ni = 0; ni < 4; ++ni) {
        const int ra = wm + ni * 16 + rl;
        wf[ni] = *(const bf16x8*)&lA[((tap * 128 + ra) * 4 + (kc ^ ((ra >> 1) & 3))) * 8];
      }
      #pragma unroll
      for (int mi = 0; mi < 8; ++mi) {
        const int rb = wn + mi * 16 + rl + tap;
        xf[mi] = *(const bf16x8*)&lB[(rb * 4 + (kc ^ ((rb >> 1) & 3))) * 8];
      }
      #pragma unroll
      for (int mi = 0; mi < 8; ++mi)
        #pragma unroll
        for (int ni = 0; ni < 4; ++ni)
          acc[mi][ni] = __builtin_amdgcn_mfma_f32_16x16x32_bf16(xf[mi], wf[ni], acc[mi][ni], 0, 0, 0);
    }
  }

  // epilogue: D col = lane&15 -> o; row = (lane>>4)*4+reg -> t (f32x4 stores)
  const int ccol = lane & 15;
  const int trow = (lane >> 4) * 4;
  float dmv[4];
  #pragma unroll
  for (int ni = 0; ni < 4; ++ni)
    dmv[ni] = demod[(size_t)b * 512 + o0 + wm + ni * 16 + ccol];
  float* ob = out + ((size_t)b * COUT + o0 + wm + ccol) * T_ + t0 + wn + trow;
  #pragma unroll
  for (int mi = 0; mi < 8; ++mi)
    #pragma unroll
    for (int ni = 0; ni < 4; ++ni) {
      f32x4 v = acc[mi][ni];
      v.x *= dmv[ni]; v.y *= dmv[ni]; v.z *= dmv[ni]; v.w *= dmv[ni];
      *(f32x4*)&ob[(size_t)ni * 16 * T_ + mi * 16] = v;
    }
}

// ---------------------------------------------------------------------------
extern "C" void kernel_launch(void* const* d_in, const int* in_sizes, int n_in,
                              void* d_out, int out_size, void* d_ws, size_t ws_size,
                              hipStream_t stream) {
  const float* x       = (const float*)d_in[0];   // [16,512,2048]
  const float* c_src   = (const float*)d_in[1];   // [16,128]
  const float* c_trg   = (const float*)d_in[2];   // [16,128]
  const float* style_w = (const float*)d_in[3];   // [512,256]
  const float* style_b = (const float*)d_in[4];   // [512]
  const float* weight  = (const float*)d_in[5];   // [1,512,512,3]
  float* out = (float*)d_out;

  // workspace: demod fp32 [16][512] @32768; Wb bf16 [3][512][512] @65536;
  //            xT bf16 [16][2050][512] @1638400
  char* ws = (char*)d_ws;
  float* demod_buf      = (float*)(ws + 32768);
  unsigned short* Wb    = (unsigned short*)(ws + 65536);
  unsigned short* xTbuf = (unsigned short*)(ws + 65536 + 1572864);

  fused_prep_kernel<<<dim3(1600), 256, 0, stream>>>(x, c_src, c_trg, style_w,
                                                    style_b, weight, xTbuf,
                                                    demod_buf, Wb);
  gemm_kernel<<<dim3(512), 256, 0, stream>>>(Wb, xTbuf, demod_buf, out);
}

// Round 12
// 182.983 us; speedup vs baseline: 1.1426x; 1.1426x over previous
//
#include <hip/hip_runtime.h>
#include <cstdint>
#include <cstddef>

// ---------------------------------------------------------------------------
// Style2ResidualBlock1DSrc: modulated conv1d (StyleGAN2-style) on MI355X.
// R14 = R12 verbatim restore (session best, 179.7us measured).
//  R13 post-mortem: per-block s-recompute was latency-bound (VALUBusy 4.8%,
//  64-way scattered style_w row reads, 4x less block parallelism) -> 209us.
//  Redundant-recompute falsified on both axes (R6 occupancy-pinned fusion,
//  R13 scattered recompute). The 3-dispatch R12 architecture is the verified
//  fixed point:
//   - style_kernel: 1.4us, coalesced.
//   - fused_prep: transpose(4096 blocks, 1 tile each) | demod(512, svs-less),
//     single dispatch, no grid barrier (independent stages).
//   - gemm: frozen R11/R12 structure (2-barrier, chunk-swizzled LDS, swapped
//     operands, f32x4 epilogue) - 56.5us = m97-structure ceiling; 6 schedule
//     variants measured 54-62; 8-phase escape killed 2 containers.
// Factorization: A = bf16 Wb[3][512][512] L2-resident, s folded into xT,
// demod applied in fp32 epilogue.
// ---------------------------------------------------------------------------

#define LIN_SCALE  0.0625f           // 1/sqrt(256)
#define CONV_SCALE 0.014731391f      // 1/sqrt(512*9)

#define B_   16
#define CIN  512
#define COUT 512
#define T_   2048
#define TP   2050                    // T + 2 pad rows

typedef __bf16 bf16x8 __attribute__((ext_vector_type(8)));
typedef float  f32x4  __attribute__((ext_vector_type(4)));
typedef unsigned short u16x8 __attribute__((ext_vector_type(8)));
typedef unsigned short u16x2 __attribute__((ext_vector_type(2)));

#define AS1 __attribute__((address_space(1)))
#define AS3 __attribute__((address_space(3)))

__device__ inline unsigned short f2bf(float f) {
  __bf16 h = (__bf16)f;              // RNE fptrunc
  return __builtin_bit_cast(unsigned short, h);
}

// ---------------- 1. style linear: s[b][i] ----------------
__global__ __launch_bounds__(256) void style_kernel(const float* __restrict__ c_src,
                                                    const float* __restrict__ c_trg,
                                                    const float* __restrict__ sw,
                                                    const float* __restrict__ sb,
                                                    float* __restrict__ s) {
  __shared__ float c[256];
  const int b = blockIdx.y;
  const int tid = threadIdx.x;
  c[tid] = (tid < 128) ? c_src[b * 128 + tid] : c_trg[b * 128 + tid - 128];
  __syncthreads();
  const int w = tid >> 6, lane = tid & 63;
  #pragma unroll
  for (int rr = 0; rr < 16; ++rr) {
    const int i = blockIdx.x * 64 + w * 16 + rr;
    const float* row = sw + (size_t)i * 256;
    float acc = row[lane] * c[lane] + row[lane + 64] * c[lane + 64]
              + row[lane + 128] * c[lane + 128] + row[lane + 192] * c[lane + 192];
    #pragma unroll
    for (int off = 32; off; off >>= 1) acc += __shfl_down(acc, off, 64);
    if (lane == 0) s[b * 512 + i] = acc * LIN_SCALE + sb[i];
  }
}

// ---------------- 2. fused prep: transpose(4096 blocks) | demod(512 blocks) ----------------
// ids [0,4096): transpose+pad+s-modulate tile (R4 body verbatim, flat smem).
// ids [4096,4608): demod[b][o] + Wb row (svs-less: direct L2 s reads).
__global__ __launch_bounds__(256) void fused_prep_kernel(const float* __restrict__ x,
                                                         const float* __restrict__ s,
                                                         const float* __restrict__ weight,
                                                         unsigned short* __restrict__ xT,
                                                         float* __restrict__ demod,
                                                         unsigned short* __restrict__ Wb) {
  __shared__ __align__(16) char smem[16896];   // union: transpose 16896 | demod 6400
  const int id  = blockIdx.x;
  const int tid = threadIdx.x;

  if (id < 4096) {
    // ------------------ transpose path (verbatim R4 logic) ------------------
    float* tile = (float*)smem;                // [64][65]
    float* ss   = (float*)(smem + 16640);      // [64]
    const int t0 = (id & 31) * 64;
    const int i0 = ((id >> 5) & 7) * 64;
    const int b  = id >> 8;

    if (tid < 64) ss[tid] = s[(size_t)b * 512 + i0 + tid];

    const int lr = tid >> 4;            // 0..15
    const int lc = (tid & 15) * 4;      // float4
    const float* xb = x + ((size_t)b * CIN + i0) * T_ + t0;
    #pragma unroll
    for (int p = 0; p < 4; ++p) {
      const int r = p * 16 + lr;
      const float4 v = *(const float4*)(xb + (size_t)r * T_ + lc);
      tile[r * 65 + lc + 0] = v.x; tile[r * 65 + lc + 1] = v.y;
      tile[r * 65 + lc + 2] = v.z; tile[r * 65 + lc + 3] = v.w;
    }
    // fused zero-pad of rows 0 and 2049 (no barrier dependency)
    if (t0 == 0 && tid < 8)
      *(u16x8*)&xT[(size_t)b * TP * CIN + i0 + tid * 8] = (u16x8){0,0,0,0,0,0,0,0};
    if (t0 == T_ - 64 && tid < 8)
      *(u16x8*)&xT[((size_t)b * TP + TP - 1) * CIN + i0 + tid * 8] = (u16x8){0,0,0,0,0,0,0,0};
    __syncthreads();

    const int st = tid >> 3;            // 0..31
    const int si = (tid & 7) * 8;       // 16B
    float sv[8];
    #pragma unroll
    for (int q = 0; q < 8; ++q) sv[q] = ss[si + q];
    unsigned short* xTb = xT + ((size_t)b * TP + 1 + t0) * CIN + i0;
    #pragma unroll
    for (int p = 0; p < 2; ++p) {
      const int t = p * 32 + st;
      u16x8 v;
      #pragma unroll
      for (int q = 0; q < 8; ++q) v[q] = f2bf(tile[(si + q) * 65 + t] * sv[q]);
      *(u16x8*)&xTb[(size_t)t * CIN + si] = v;
    }
  } else {
    // ------------------ demod path (svs-less) ------------------
    const int o = id - 4096;
    float* wsh     = (float*)smem;             // 1536 floats
    float* partial = (float*)(smem + 6144);    // [16][4]

    #pragma unroll
    for (int j = tid; j < 384; j += 256)
      ((float4*)wsh)[j] = ((const float4*)(weight + (size_t)o * 1536))[j];
    __syncthreads();

    float wr[6];
    #pragma unroll
    for (int q = 0; q < 6; ++q) wr[q] = wsh[tid * 6 + q] * CONV_SCALE;

    // batch-independent bf16 base weight: Wb[k][o][i], i = 2*tid, 2*tid+1
    #pragma unroll
    for (int k = 0; k < 3; ++k) {
      u16x2 v;
      v.x = f2bf(wr[k]);
      v.y = f2bf(wr[3 + k]);
      *(u16x2*)&Wb[((size_t)(k * 512 + o)) * 512 + 2 * tid] = v;
    }

    // direct L2 s reads (s is 32KB, style-hot); identical FMA order to R4
    float s0v[16], s1v[16];
    #pragma unroll
    for (int b = 0; b < 16; ++b) {
      s0v[b] = s[b * 512 + 2 * tid];
      s1v[b] = s[b * 512 + 2 * tid + 1];
    }

    const int lane = tid & 63, w = tid >> 6;
    float ssb[16];
    #pragma unroll
    for (int b = 0; b < 16; ++b) {
      float ssq = 0.f;
      #pragma unroll
      for (int q = 0; q < 3; ++q) { float v = wr[q] * s0v[b]; ssq += v * v; }
      #pragma unroll
      for (int q = 3; q < 6; ++q) { float v = wr[q] * s1v[b]; ssq += v * v; }
      ssb[b] = ssq;
    }
    #pragma unroll
    for (int b = 0; b < 16; ++b) {
      float ssq = ssb[b];
      #pragma unroll
      for (int off = 32; off; off >>= 1) ssq += __shfl_down(ssq, off, 64);
      if (lane == 0) partial[b * 4 + w] = ssq;
    }
    __syncthreads();
    if (tid < 16)
      demod[(size_t)tid * 512 + o] =
          rsqrtf(partial[tid * 4] + partial[tid * 4 + 1] + partial[tid * 4 + 2]
               + partial[tid * 4 + 3] + 1e-8f);
  }
}

// ---------------- 3. main GEMM: R11/R12 frozen (2-barrier, swapped operands) ----------------
// out[b][o0+wm+ni*16+oc][t0+wn+mi*16+tr..+3] = demod * acc[mi][ni]
// acc = mfma(xT_frag (A-op, t rows), Wb_frag (B-op, o cols)) -> D rows = t.
// Staging: lA[3][128][32], lB[258][32], chunk-swz c^((row>>1)&3).
__global__ __launch_bounds__(256, 2) void gemm_kernel(const unsigned short* __restrict__ Wb,
                                                      const unsigned short* __restrict__ xT,
                                                      const float* __restrict__ demod,
                                                      float* __restrict__ out) {
  __shared__ unsigned short lA[3 * 128 * 32];   // 24576 B
  __shared__ unsigned short lB[258 * 32];       // 16512 B

  // XCD b-grouping: 512 blocks; ids == xcd (mod 8); 2 batches per XCD.
  const int id  = blockIdx.x;
  const int xcd = id & 7;
  const int j   = id >> 3;                 // 0..63
  const int b   = xcd + 8 * (j >> 5);      // 0..15
  const int r   = j & 31;
  const int o0  = (r >> 3) * 128;          // 4 o-blocks
  const int t0  = (r & 7) * 256;           // 8 t-blocks

  const int tid  = threadIdx.x;
  const int lane = tid & 63;
  const int wm   = ((tid >> 6) & 1) * 64;  // wave o offset
  const int wn   = (tid >> 7) * 128;       // wave t offset
  const int rl   = lane & 15;
  const int kc   = lane >> 4;              // chunk 0..3 within 32-wide row

  const unsigned short* gW = Wb + (size_t)o0 * 512;            // batch-independent
  const unsigned short* gX = xT + ((size_t)b * TP + t0) * CIN;

  f32x4 acc[8][4];                         // [t-frag][o-frag]
  #pragma unroll
  for (int i = 0; i < 8; ++i)
    #pragma unroll
    for (int jj = 0; jj < 4; ++jj) acc[i][jj] = (f32x4){0.f, 0.f, 0.f, 0.f};

  for (int kk = 0; kk < 16; ++kk) {
    const int i0 = kk * 32;
    __syncthreads();                       // previous compute done
    // A: 1536 16B-chunks, 6 per thread. chunk ci=(tap*128+ar)*4+c
    #pragma unroll
    for (int q = 0; q < 6; ++q) {
      const int ci  = q * 256 + tid;
      const int row = ci >> 2;             // tap*128 + ar
      const int tap = row >> 7;
      const int ar  = row & 127;
      const int gc  = ((ci & 3) ^ ((ar >> 1) & 3)) * 8;
      __builtin_amdgcn_global_load_lds(
          (const AS1 void*)(gW + (size_t)tap * 262144 + (size_t)ar * 512 + i0 + gc),
          (AS3 void*)(&lA[ci * 8]), 16, 0, 0);
    }
    // B: 258 rows x 4 chunks = 1032; 4 per thread + tail 8
    #pragma unroll
    for (int q = 0; q < 4; ++q) {
      const int ci  = q * 256 + tid;
      const int row = ci >> 2;
      const int gc  = ((ci & 3) ^ ((row >> 1) & 3)) * 8;
      __builtin_amdgcn_global_load_lds(
          (const AS1 void*)(gX + (size_t)row * CIN + i0 + gc),
          (AS3 void*)(&lB[ci * 8]), 16, 0, 0);
    }
    if (tid < 8) {
      const int ci  = 1024 + tid;
      const int row = ci >> 2;             // 256, 257
      const int gc  = ((ci & 3) ^ ((row >> 1) & 3)) * 8;
      __builtin_amdgcn_global_load_lds(
          (const AS1 void*)(gX + (size_t)row * CIN + i0 + gc),
          (AS3 void*)(&lB[ci * 8]), 16, 0, 0);
    }
    __syncthreads();                       // staging visible

    #pragma unroll
    for (int tap = 0; tap < 3; ++tap) {
      bf16x8 wf[4], xf[8];
      #pragma unroll
      for (int ni = 0; ni < 4; ++ni) {
        const int ra = wm + ni * 16 + rl;
        wf[ni] = *(const bf16x8*)&lA[((tap * 128 + ra) * 4 + (kc ^ ((ra >> 1) & 3))) * 8];
      }
      #pragma unroll
      for (int mi = 0; mi < 8; ++mi) {
        const int rb = wn + mi * 16 + rl + tap;
        xf[mi] = *(const bf16x8*)&lB[(rb * 4 + (kc ^ ((rb >> 1) & 3))) * 8];
      }
      #pragma unroll
      for (int mi = 0; mi < 8; ++mi)
        #pragma unroll
        for (int ni = 0; ni < 4; ++ni)
          acc[mi][ni] = __builtin_amdgcn_mfma_f32_16x16x32_bf16(xf[mi], wf[ni], acc[mi][ni], 0, 0, 0);
    }
  }

  // epilogue: D col = lane&15 -> o; row = (lane>>4)*4+reg -> t (f32x4 stores)
  const int ccol = lane & 15;
  const int trow = (lane >> 4) * 4;
  float dmv[4];
  #pragma unroll
  for (int ni = 0; ni < 4; ++ni)
    dmv[ni] = demod[(size_t)b * 512 + o0 + wm + ni * 16 + ccol];
  float* ob = out + ((size_t)b * COUT + o0 + wm + ccol) * T_ + t0 + wn + trow;
  #pragma unroll
  for (int mi = 0; mi < 8; ++mi)
    #pragma unroll
    for (int ni = 0; ni < 4; ++ni) {
      f32x4 v = acc[mi][ni];
      v.x *= dmv[ni]; v.y *= dmv[ni]; v.z *= dmv[ni]; v.w *= dmv[ni];
      *(f32x4*)&ob[(size_t)ni * 16 * T_ + mi * 16] = v;
    }
}

// ---------------------------------------------------------------------------
extern "C" void kernel_launch(void* const* d_in, const int* in_sizes, int n_in,
                              void* d_out, int out_size, void* d_ws, size_t ws_size,
                              hipStream_t stream) {
  const float* x       = (const float*)d_in[0];   // [16,512,2048]
  const float* c_src   = (const float*)d_in[1];   // [16,128]
  const float* c_trg   = (const float*)d_in[2];   // [16,128]
  const float* style_w = (const float*)d_in[3];   // [512,256]
  const float* style_b = (const float*)d_in[4];   // [512]
  const float* weight  = (const float*)d_in[5];   // [1,512,512,3]
  float* out = (float*)d_out;

  // workspace: s fp32 [16][512] @0; demod fp32 [16][512] @32768;
  //            Wb bf16 [3][512][512] @65536; xT bf16 [16][2050][512] @1638400
  char* ws = (char*)d_ws;
  float* s_buf          = (float*)ws;
  float* demod_buf      = (float*)(ws + 32768);
  unsigned short* Wb    = (unsigned short*)(ws + 65536);
  unsigned short* xTbuf = (unsigned short*)(ws + 65536 + 1572864);

  style_kernel<<<dim3(8, 16), 256, 0, stream>>>(c_src, c_trg, style_w, style_b, s_buf);
  fused_prep_kernel<<<dim3(4608), 256, 0, stream>>>(x, s_buf, weight, xTbuf,
                                                    demod_buf, Wb);
  gemm_kernel<<<dim3(512), 256, 0, stream>>>(Wb, xTbuf, demod_buf, out);
}